// Round 9
// baseline (142923.206 us; speedup 1.0000x reference)
//
#include <hip/hip_runtime.h>
#include <hip/hip_fp16.h>

// ---------------- parameters (all inputs fp32; output fp32) ----------------
struct P19 {
  const float *src;
  const float *eWih0, *eWhh0, *ebih0, *ebhh0;
  const float *eWih1, *eWhh1, *ebih1, *ebhh1;
  const float *dWih0, *dWhh0, *dbih0, *dbhh0;
  const float *dWih1, *dWhh1, *dbih1, *dbhh1;
  const float *fcW, *fcb;
  float *out;
  float *ws;
};

typedef _Float16 h2v __attribute__((ext_vector_type(2)));

__device__ __forceinline__ float sigf(float x) { return 1.f / (1.f + __expf(-x)); }

__device__ __forceinline__ unsigned packh(float a, float b2) {
  __half2 h2 = __floats2half2_rn(a, b2);
  return *(const unsigned *)&h2;
}

// ---------------- session ledger (r0..r8) ---------------------------------
// r0 (12.38 ms, PROVEN): 256 blk x 256 thr, (256,1), 108 VGPR, agent-scope
//   uncached h loads, fenceless flag barrier. VALUBusy 27%, round 16.6 us.
// r1/r8 (both PASSED, both 37 ms): cached h loads (plain in r1, workgroup-
//   atomic in r8) + agent acquire fence. Protocol CORRECT both times
//   (absmax 2.44e-4) but scheduler software-pipelined the now-hoistable
//   loads across chunk boundaries -> VGPR 256 + ~42 GB scratch writes.
//   Lesson: agent-scope sc0sc1 atomics did double duty: coherence AND
//   schedule pinning. Separate the two concerns.
// r2/r4/r6: any launch_bounds promising >=2 waves/EU caps VGPR at 128 ->
//   identical 188 GB spill across three chunk shapes. TLP arc dead.
// r5: (256,1) at 512 blocks -> VGPR>128 -> residency broke -> wrong answer.
// THIS round (r9): r8's validated protocol + compile-time schedule pinning:
//   __builtin_amdgcn_sched_barrier(0) between every load-chunk and
//   compute-chunk phase in dotq1/dotq2. Zero runtime cost; blocks exactly
//   the scheduler motion that exploded regalloc; compiler still emits its
//   own correctly-counted vmcnt waits for the chunk loads.
//   Expected: VGPR 110-150, WRITE ~0.14 GB. If VGPR=256/GB-scale writes
//   again -> cached-read arc dead for good -> revert to r0 verbatim.
__device__ __forceinline__ unsigned ldh(const unsigned *p) {  // uncached (flags)
  return __hip_atomic_load((const unsigned *)p, __ATOMIC_RELAXED, __HIP_MEMORY_SCOPE_AGENT);
}
// cached-but-atomic h read: workgroup scope -> plain cached global_load_dword
// (freshness via the per-round acquire fence in waitbar).
__device__ __forceinline__ unsigned ldw(const unsigned *p) {
  return __hip_atomic_load((const unsigned *)p, __ATOMIC_RELAXED, __HIP_MEMORY_SCOPE_WORKGROUP);
}
__device__ __forceinline__ void sth(unsigned *p, unsigned v) {
  __hip_atomic_store(p, v, __ATOMIC_RELAXED, __HIP_MEMORY_SCOPE_AGENT);
}
__device__ __forceinline__ void sthf(float *p, float v) {
  __hip_atomic_store(p, v, __ATOMIC_RELAXED, __HIP_MEMORY_SCOPE_AGENT);
}
__device__ __forceinline__ float ldhf(const float *p) {
  return __hip_atomic_load((const float *)p, __ATOMIC_RELAXED, __HIP_MEMORY_SCOPE_AGENT);
}

__device__ __forceinline__ float dot2(unsigned h, unsigned w, float acc) {
#if __has_builtin(__builtin_amdgcn_fdot2)
  return __builtin_amdgcn_fdot2(*(h2v *)&h, *(h2v *)&w, acc, false);
#else
  float2 hf = __half22float2(*(const __half2 *)&h);
  float2 wf = __half22float2(*(const __half2 *)&w);
  return fmaf(hf.x, wf.x, fmaf(hf.y, wf.y, acc));
#endif
}

#define SB() __builtin_amdgcn_sched_barrier(0)

// ---- split-phase distributed-flag grid barrier ---------------------------
__device__ __forceinline__ void arrive(unsigned *flags, unsigned gen, int tid, int blk) {
  __syncthreads();  // drains vmcnt(0) per wave: all agent-stores are in L3
  if (tid == 0) sth(flags + blk * 32, gen);
}
__device__ __forceinline__ void waitbar(unsigned *flags, unsigned gen, int tid) {
  {
    unsigned *f = flags + tid * 32;
    int g = 0;
    while (ldh(f) < gen) {
      __builtin_amdgcn_s_sleep(8);
      if (++g > (1 << 16)) break;  // safety: never deadlock the bench
    }
  }
  // acquire: invalidate clean L1/L2 lines so the CACHED h reads below pull
  // the write-through (L3) data. Validated correct in r1 and r8.
  __builtin_amdgcn_fence(__ATOMIC_ACQUIRE, "agent");
  __syncthreads();  // all threads saw their flag + caches invalidated
}

// ---- half-dots: thread covers BOTH units (8 gate-rows) over 128 k2 -------
// r0's proven 4-chunk double-buffer order, loads cached (ldw), every phase
// boundary pinned with sched_barrier(0) so the scheduler cannot hoist
// chunk loads across compute (the r1/r8 VGPR-explosion mechanism).
__device__ __forceinline__ void dotq1(float *A, const uint4 *__restrict__ wq,
                                      const unsigned *__restrict__ hq) {
  unsigned ca[32], cb[32];
#define LOADQ1(dst, base) \
  _Pragma("unroll") for (int c = 0; c < 32; ++c) dst[c] = ldw(hq + ((base) + c) * 128);
#define COMP1(src, base) \
  _Pragma("unroll") for (int c = 0; c < 32; ++c) { \
    int k2 = (base) + c; \
    uint4 w0 = wq[k2 * 2], w1 = wq[k2 * 2 + 1]; \
    unsigned h = src[c]; \
    A[0] = dot2(h, w0.x, A[0]); A[1] = dot2(h, w0.y, A[1]); \
    A[2] = dot2(h, w0.z, A[2]); A[3] = dot2(h, w0.w, A[3]); \
    A[4] = dot2(h, w1.x, A[4]); A[5] = dot2(h, w1.y, A[5]); \
    A[6] = dot2(h, w1.z, A[6]); A[7] = dot2(h, w1.w, A[7]); \
  }
  LOADQ1(ca, 0)  SB();
  LOADQ1(cb, 32) SB();
  COMP1(ca, 0)   SB();
  LOADQ1(ca, 64) SB();
  COMP1(cb, 32)  SB();
  LOADQ1(cb, 96) SB();
  COMP1(ca, 64)  SB();
  COMP1(cb, 96)  SB();
#undef LOADQ1
#undef COMP1
}
__device__ __forceinline__ void dotq2(float *A, const uint4 *__restrict__ w0q,
                                      const uint4 *__restrict__ w1q,
                                      const unsigned *__restrict__ hq) {
  unsigned ca[32], cb[32];
#define LOADQ2(dst, base) \
  _Pragma("unroll") for (int c = 0; c < 32; ++c) dst[c] = ldw(hq + ((base) + c) * 128);
#define COMP2(src, base) \
  _Pragma("unroll") for (int c = 0; c < 32; ++c) { \
    int k2 = (base) + c; \
    uint4 a0 = w0q[k2 * 2], a1 = w0q[k2 * 2 + 1]; \
    uint4 b0 = w1q[k2 * 2], b1 = w1q[k2 * 2 + 1]; \
    unsigned h = src[c]; \
    A[0] = dot2(h, a0.x, A[0]);   A[1] = dot2(h, a0.y, A[1]); \
    A[2] = dot2(h, a0.z, A[2]);   A[3] = dot2(h, a0.w, A[3]); \
    A[4] = dot2(h, a1.x, A[4]);   A[5] = dot2(h, a1.y, A[5]); \
    A[6] = dot2(h, a1.z, A[6]);   A[7] = dot2(h, a1.w, A[7]); \
    A[8] = dot2(h, b0.x, A[8]);   A[9] = dot2(h, b0.y, A[9]); \
    A[10] = dot2(h, b0.z, A[10]); A[11] = dot2(h, b0.w, A[11]); \
    A[12] = dot2(h, b1.x, A[12]); A[13] = dot2(h, b1.y, A[13]); \
    A[14] = dot2(h, b1.z, A[14]); A[15] = dot2(h, b1.w, A[15]); \
  }
  LOADQ2(ca, 0)  SB();
  LOADQ2(cb, 32) SB();
  COMP2(ca, 0)   SB();
  LOADQ2(ca, 64) SB();
  COMP2(cb, 32)  SB();
  LOADQ2(cb, 96) SB();
  COMP2(ca, 64)  SB();
  COMP2(cb, 96)  SB();
#undef LOADQ2
#undef COMP2
}

__device__ __forceinline__ void fc_emit(const unsigned *__restrict__ h1buf,
                                        const float *__restrict__ fcW,
                                        const float *__restrict__ fcb,
                                        float *__restrict__ out, int sIdx,
                                        int tid, int blk) {
  int q = tid >> 6, l = tid & 63;
  if (q < 3) {
    int o = blk * 3 + q, j = o >> 7, bb = o & 127;
    const unsigned *hc = h1buf + bb;
    const float2 *fw = (const float2 *)(fcW + j * 512);
    float acc = 0.f;
#pragma unroll
    for (int r = 0; r < 4; ++r) {
      int k2 = l + r * 64;
      unsigned d = ldw(hc + k2 * 128);
      float2 hf = __half22float2(*(const __half2 *)&d);
      float2 wv = fw[k2];
      acc = fmaf(wv.x, hf.x, acc);
      acc = fmaf(wv.y, hf.y, acc);
    }
#pragma unroll
    for (int off = 32; off; off >>= 1) acc += __shfl_down(acc, off, 64);
    if (l == 0) out[((size_t)bb * 256 + sIdx) * 6 + j] = acc + fcb[j];
  }
}

__global__ __launch_bounds__(256, 1) void seq2seq_kernel(P19 p) {
  const int tid = threadIdx.x;
  const int blk = blockIdx.x;
  const int b = tid & 127;   // batch lane
  const int kh = tid >> 7;   // k-half 0..1

  float *ws = p.ws;
  unsigned *flags = (unsigned *)ws;  // 256 flags, 128B-spaced
  unsigned *hpB = (unsigned *)(ws + 8256);
  unsigned *hp0r[2] = {hpB, hpB + 32768};           // h0 parity, [k2][b]
  unsigned *hp1r[2] = {hpB + 65536, hpB + 98304};   // h1 parity
  float *outp = ws + 8256 + 131072;                 // dec seed [j][b] 6*128
  float *srcT = outp + 768;                         // [t][i][b] 256*6*128

  // LDS: 7 matrices x 256 k2 x 2 units x (4 gates half2) = 56 KiB
  __shared__ __align__(16) uint4 wl4[3584];
  __shared__ float4 redux[6][128];  // 12 KiB: kh=1 partial-dot exchange
  __shared__ float wxe[48], wxd[48], bbuf[40];
  unsigned *wl1 = (unsigned *)wl4;

  {  // ---- stage weights (fp16 pairs) into LDS, once ----
    const float *mats[6] = {p.eWhh0, p.eWih1, p.eWhh1, p.dWhh0, p.dWih1, p.dWhh1};
    for (int e = tid; e < 12288; e += 256) {
      int k2 = e & 255, r = e >> 8;       // r 0..47
      int g = r & 3, uu = (r >> 2) & 1, m = r >> 3;
      const float *row = mats[m] + (size_t)(g * 512 + blk * 2 + uu) * 512;
      wl1[(m * 512 + k2 * 2 + uu) * 4 + g] = packh(row[2 * k2], row[2 * k2 + 1]);
    }
    for (int e = tid; e < 2048; e += 256) {  // W' = dec_Wih0 @ fcW -> slot 6
      int uu = e >> 10, rem = e & 1023, g = rem & 3, k2 = rem >> 2;
      const float *wr = p.dWih0 + (size_t)(g * 512 + blk * 2 + uu) * 6;
      float v0 = 0.f, v1 = 0.f;
#pragma unroll
      for (int i = 0; i < 6; ++i) {
        v0 = fmaf(wr[i], p.fcW[i * 512 + 2 * k2], v0);
        v1 = fmaf(wr[i], p.fcW[i * 512 + 2 * k2 + 1], v1);
      }
      wl1[(6 * 512 + k2 * 2 + uu) * 4 + g] = packh(v0, v1);
    }
    if (tid < 40) {  // fused biases: be0|be1|bd1|b''|bd0
      int f = tid >> 3, k = tid & 7, uu = k >> 2, g = k & 3;
      int r2 = g * 512 + blk * 2 + uu;
      float v;
      if (f == 0) v = p.ebih0[r2] + p.ebhh0[r2];
      else if (f == 1) v = p.ebih1[r2] + p.ebhh1[r2];
      else if (f == 2) v = p.dbih1[r2] + p.dbhh1[r2];
      else {
        v = p.dbih0[r2] + p.dbhh0[r2];
        if (f == 3)
#pragma unroll
          for (int i = 0; i < 6; ++i) v = fmaf(p.dWih0[(size_t)r2 * 6 + i], p.fcb[i], v);
      }
      bbuf[tid] = v;
    } else if (tid >= 64 && tid < 112) {
      int idx = tid - 64, uu = idx / 24, rem = idx % 24, g = rem / 6, i = rem % 6;
      wxe[idx] = p.eWih0[(size_t)(g * 512 + blk * 2 + uu) * 6 + i];
    } else if (tid >= 128 && tid < 176) {
      int idx = tid - 128, uu = idx / 24, rem = idx % 24, g = rem / 6, i = rem % 6;
      wxd[idx] = p.dWih0[(size_t)(g * 512 + blk * 2 + uu) * 6 + i];
    }
  }
  // ---- init: transpose src -> srcT; seed decoder input (agent stores: ----
  // ---- cross-block reads later must see them at the coherence point)  ----
  for (int e = blk * 256 + tid; e < 196608; e += 65536) {
    int bb = e & 127, rest = e >> 7, i = rest % 6, t = rest / 6;
    sthf(&srcT[t * 768 + i * 128 + bb], p.src[((size_t)bb * 256 + t) * 6 + i]);
  }
  {
    int g0 = blk * 256 + tid;
    if (g0 < 768) {
      int bb = g0 & 127, i = g0 >> 7;
      sthf(&outp[i * 128 + bb], p.src[((size_t)bb * 256 + 255) * 6 + i]);
    }
  }
  float c0[2] = {0.f, 0.f}, c1[2] = {0.f, 0.f};
  unsigned gen = 1;
  arrive(flags, gen, tid, blk);
  waitbar(flags, gen, tid);

#define WQ(m) (wl4 + (m) * 512 + kh * 256)
#define HST(buf) ((const unsigned *)(buf) + kh * 16384 + b)
#define RADD(gb, slot) { float4 v = redux[slot][b]; \
    G[(gb)] += v.x; G[(gb) + 1] += v.y; G[(gb) + 2] += v.z; G[(gb) + 3] += v.w; }

  // ================= encoder: layer0 & layer1 pipelined (lag 1) ============
  for (int t = 0; t <= 256; ++t) {
    float A16[16], A8[8];
#pragma unroll
    for (int i = 0; i < 16; ++i) A16[i] = 0.f;
#pragma unroll
    for (int i = 0; i < 8; ++i) A8[i] = 0.f;
    dotq2(A16, WQ(0), WQ(1), HST(hp0r[t & 1]));   // eWhh0 + eWih1 share h0
    dotq1(A8, WQ(2), HST(hp1r[(t + 1) & 1]));     // eWhh1 @ h1[t-2]
    if (kh) {
      redux[0][b] = make_float4(A16[0], A16[1], A16[2], A16[3]);
      redux[1][b] = make_float4(A16[4], A16[5], A16[6], A16[7]);
      redux[2][b] = make_float4(A16[8], A16[9], A16[10], A16[11]);
      redux[3][b] = make_float4(A16[12], A16[13], A16[14], A16[15]);
      redux[4][b] = make_float4(A8[0], A8[1], A8[2], A8[3]);
      redux[5][b] = make_float4(A8[4], A8[5], A8[6], A8[7]);
    }
    __syncthreads();
    if (kh == 0) {
      float G[24];
#pragma unroll
      for (int i = 0; i < 16; ++i) G[i] = A16[i];
#pragma unroll
      for (int i = 0; i < 8; ++i) G[16 + i] = A8[i];
      { RADD(0, 0) RADD(4, 1) RADD(8, 2) RADD(12, 3) RADD(16, 4) RADD(20, 5) }
      if (t < 256) {  // layer0
        float xv[6], h0v[2];
#pragma unroll
        for (int i = 0; i < 6; ++i) xv[i] = srcT[t * 768 + i * 128 + b];
#pragma unroll
        for (int uu = 0; uu < 2; ++uu) {
          float g4[4];
#pragma unroll
          for (int g = 0; g < 4; ++g) {
            float v = G[uu * 4 + g] + bbuf[uu * 4 + g];
#pragma unroll
            for (int i = 0; i < 6; ++i) v = fmaf(wxe[uu * 24 + g * 6 + i], xv[i], v);
            g4[g] = v;
          }
          float ig = sigf(g4[0]), fg = sigf(g4[1]), gg = tanhf(g4[2]), og = sigf(g4[3]);
          c0[uu] = fg * c0[uu] + ig * gg;
          h0v[uu] = og * tanhf(c0[uu]);
        }
        sth(&hp0r[(t + 1) & 1][blk * 128 + b], packh(h0v[0], h0v[1]));
      }
      if (t >= 1) {  // layer1
        float h1v[2];
#pragma unroll
        for (int uu = 0; uu < 2; ++uu) {
          float g4[4];
#pragma unroll
          for (int g = 0; g < 4; ++g)
            g4[g] = G[8 + uu * 4 + g] + G[16 + uu * 4 + g] + bbuf[8 + uu * 4 + g];
          float ig = sigf(g4[0]), fg = sigf(g4[1]), gg = tanhf(g4[2]), og = sigf(g4[3]);
          c1[uu] = fg * c1[uu] + ig * gg;
          h1v[uu] = og * tanhf(c1[uu]);
        }
        sth(&hp1r[t & 1][blk * 128 + b], packh(h1v[0], h1v[1]));
      }
    }
    arrive(flags, ++gen, tid, blk);
    waitbar(flags, gen, tid);
  }
  // enc final: h0 in hp0r[0], h1 in hp1r[0]; c0,c1 in registers.

  // ========== decoder: 2 rounds/step, pre-dots hide barrier waits ==========
  for (int s = 0; s < 256; ++s) {
    // ---- R_A: dec layer0 (+ W'@h1 fused fc; saves Whh1d partial for R_B) --
    float A3[8];
#pragma unroll
    for (int i = 0; i < 8; ++i) A3[i] = 0.f;
    dotq1(A3, WQ(3), HST(hp0r[s & 1]));  // pre-wait: covered by last round's inv
    if (s) waitbar(flags, gen, tid);
    float AA[16];
#pragma unroll
    for (int i = 0; i < 16; ++i) AA[i] = 0.f;
    if (s == 0) {
      dotq1(AA + 8, WQ(5), HST(hp1r[0]));  // Whh1d partial only
    } else {
      dotq2(AA, WQ(6), WQ(5), HST(hp1r[s & 1]));  // W' + Whh1d share h1
      fc_emit(hp1r[s & 1], p.fcW, p.fcb, p.out, s - 1, tid, blk);
    }
    if (kh) {
      redux[0][b] = make_float4(A3[0], A3[1], A3[2], A3[3]);
      redux[1][b] = make_float4(A3[4], A3[5], A3[6], A3[7]);
      redux[2][b] = make_float4(AA[0], AA[1], AA[2], AA[3]);
      redux[3][b] = make_float4(AA[4], AA[5], AA[6], AA[7]);
    }
    __syncthreads();
    if (kh == 0) {
      float G[8];
#pragma unroll
      for (int i = 0; i < 8; ++i) G[i] = A3[i] + AA[i];
      { RADD(0, 0) RADD(4, 1) RADD(0, 2) RADD(4, 3) }
      float bq[8];
      if (s == 0) {
        float xv[6];
#pragma unroll
        for (int i = 0; i < 6; ++i) xv[i] = ldhf(&outp[i * 128 + b]);
#pragma unroll
        for (int k = 0; k < 8; ++k) {
          int uu = k >> 2, g = k & 3;
          float v = bbuf[32 + k];
#pragma unroll
          for (int i = 0; i < 6; ++i) v = fmaf(wxd[uu * 24 + g * 6 + i], xv[i], v);
          bq[k] = v;
        }
      } else {
#pragma unroll
        for (int k = 0; k < 8; ++k) bq[k] = bbuf[24 + k];
      }
      float h0v[2];
#pragma unroll
      for (int uu = 0; uu < 2; ++uu) {
        float ig = sigf(G[uu * 4 + 0] + bq[uu * 4 + 0]);
        float fg = sigf(G[uu * 4 + 1] + bq[uu * 4 + 1]);
        float gg = tanhf(G[uu * 4 + 2] + bq[uu * 4 + 2]);
        float og = sigf(G[uu * 4 + 3] + bq[uu * 4 + 3]);
        c0[uu] = fg * c0[uu] + ig * gg;
        h0v[uu] = og * tanhf(c0[uu]);
      }
      sth(&hp0r[(s + 1) & 1][blk * 128 + b], packh(h0v[0], h0v[1]));
    }
    arrive(flags, ++gen, tid, blk);
    // ---- R_B: dec layer1 = Whh1d-partial (saved) + Wih1d @ h0[s] (new) ----
    waitbar(flags, gen, tid);
    float A4[8];
#pragma unroll
    for (int i = 0; i < 8; ++i) A4[i] = AA[8 + i];  // saved partial
    dotq1(A4, WQ(4), HST(hp0r[(s + 1) & 1]));
    if (kh) {
      redux[0][b] = make_float4(A4[0], A4[1], A4[2], A4[3]);
      redux[1][b] = make_float4(A4[4], A4[5], A4[6], A4[7]);
    }
    __syncthreads();
    if (kh == 0) {
      float G[8];
#pragma unroll
      for (int i = 0; i < 8; ++i) G[i] = A4[i];
      { RADD(0, 0) RADD(4, 1) }
      float h1v[2];
#pragma unroll
      for (int uu = 0; uu < 2; ++uu) {
        float ig = sigf(G[uu * 4 + 0] + bbuf[16 + uu * 4 + 0]);
        float fg = sigf(G[uu * 4 + 1] + bbuf[16 + uu * 4 + 1]);
        float gg = tanhf(G[uu * 4 + 2] + bbuf[16 + uu * 4 + 2]);
        float og = sigf(G[uu * 4 + 3] + bbuf[16 + uu * 4 + 3]);
        c1[uu] = fg * c1[uu] + ig * gg;
        h1v[uu] = og * tanhf(c1[uu]);
      }
      sth(&hp1r[(s + 1) & 1][blk * 128 + b], packh(h1v[0], h1v[1]));
    }
    arrive(flags, ++gen, tid, blk);
  }
  waitbar(flags, gen, tid);
  fc_emit(hp1r[0], p.fcW, p.fcb, p.out, 255, tid, blk);  // tail out[255]
}

extern "C" void kernel_launch(void *const *d_in, const int *in_sizes, int n_in,
                              void *d_out, int out_size, void *d_ws, size_t ws_size,
                              hipStream_t stream) {
  (void)in_sizes; (void)n_in; (void)out_size; (void)ws_size;
  P19 p;
  p.src = (const float *)d_in[0];
  p.eWih0 = (const float *)d_in[1];  p.eWhh0 = (const float *)d_in[2];
  p.ebih0 = (const float *)d_in[3];  p.ebhh0 = (const float *)d_in[4];
  p.eWih1 = (const float *)d_in[5];  p.eWhh1 = (const float *)d_in[6];
  p.ebih1 = (const float *)d_in[7];  p.ebhh1 = (const float *)d_in[8];
  p.dWih0 = (const float *)d_in[9];  p.dWhh0 = (const float *)d_in[10];
  p.dbih0 = (const float *)d_in[11]; p.dbhh0 = (const float *)d_in[12];
  p.dWih1 = (const float *)d_in[13]; p.dWhh1 = (const float *)d_in[14];
  p.dbih1 = (const float *)d_in[15]; p.dbhh1 = (const float *)d_in[16];
  p.fcW = (const float *)d_in[17];   p.fcb = (const float *)d_in[18];
  p.out = (float *)d_out;
  p.ws = (float *)d_ws;

  // zero flags + 4 packed-h parity buffers (outp/srcT written by kernel init)
  hipMemsetAsync(d_ws, 0, (size_t)(8256 + 4 * 32768) * sizeof(float), stream);
  seq2seq_kernel<<<dim3(256), dim3(256), 0, stream>>>(p);
}

// Round 10
// 12391.541 us; speedup vs baseline: 11.5339x; 11.5339x over previous
//
#include <hip/hip_runtime.h>
#include <hip/hip_fp16.h>

// ---------------- parameters (all inputs fp32; output fp32) ----------------
struct P19 {
  const float *src;
  const float *eWih0, *eWhh0, *ebih0, *ebhh0;
  const float *eWih1, *eWhh1, *ebih1, *ebhh1;
  const float *dWih0, *dWhh0, *dbih0, *dbhh0;
  const float *dWih1, *dWhh1, *dbih1, *dbhh1;
  const float *fcW, *fcb;
  float *out;
  float *ws;
};

typedef _Float16 h2v __attribute__((ext_vector_type(2)));

__device__ __forceinline__ float sigf(float x) { return 1.f / (1.f + __expf(-x)); }

__device__ __forceinline__ unsigned packh(float a, float b2) {
  __half2 h2 = __floats2half2_rn(a, b2);
  return *(const unsigned *)&h2;
}

// ---------------- session ledger (r0..r9) — why this is r0 verbatim -------
// r0 (12.38 ms, PROVEN): this kernel. 108 VGPR, agent-scope uncached h
//   loads, fenceless flag barrier. VALUBusy 27%, round 16.6 us.
// r1/r8/r9 (cached-read arc, 3 variants): plain loads, workgroup-atomic
//   loads, workgroup-atomic + sched_barrier(0) pinning. ALL -> VGPR 256 +
//   42-186 GB scratch spill (37-143 ms). Root cause: register-pressure
//   explosion happens in pre-RA scheduling/regalloc, which neither atomic
//   scope nor sched_barrier partitions. ONLY the sc0sc1 agent-scope
//   atomics' opacity keeps live ranges short. Cached-read arc DEAD.
// r2/r4/r6 (TLP-via-occupancy arc): any launch_bounds promising >=2
//   waves/EU caps VGPR at 128 -> identical 188 GB spill across three
//   different chunk shapes. r5: undeclared (256,1) at 512 blocks ->
//   VGPR>128 broke co-residency -> wrong answer. TLP arc DEAD.
// Verdict (pre-committed in r8): bank the proven best. The remaining
// 12 us/round stall is uncached-L3 broadcast latency + barrier
// propagation; fixing it requires LDS-staging or MFMA restructuring that
// this compiler's regalloc behavior makes high-risk. 12.38 ms is the floor
// this session can certify.

// Uncached (L3 coherence-point) accessors. AGENT-scope relaxed atomics emit
// sc0+sc1 loads/stores: bypass L1/L2, no buffer_wbl2 / buffer_inv fences.
// Cross-XCD protocol: syncthreads drains vmcnt(0) per wave (so all h stores
// are L3-visible) BEFORE the flag store; pollers read flags+h straight from
// L3 -> no stale caches, no __threadfence needed anywhere.
__device__ __forceinline__ unsigned ldh(const unsigned *p) {
  return __hip_atomic_load((const unsigned *)p, __ATOMIC_RELAXED, __HIP_MEMORY_SCOPE_AGENT);
}
__device__ __forceinline__ void sth(unsigned *p, unsigned v) {
  __hip_atomic_store(p, v, __ATOMIC_RELAXED, __HIP_MEMORY_SCOPE_AGENT);
}
__device__ __forceinline__ void sthf(float *p, float v) {
  __hip_atomic_store(p, v, __ATOMIC_RELAXED, __HIP_MEMORY_SCOPE_AGENT);
}
__device__ __forceinline__ float ldhf(const float *p) {
  return __hip_atomic_load((const float *)p, __ATOMIC_RELAXED, __HIP_MEMORY_SCOPE_AGENT);
}

__device__ __forceinline__ float dot2(unsigned h, unsigned w, float acc) {
#if __has_builtin(__builtin_amdgcn_fdot2)
  return __builtin_amdgcn_fdot2(*(h2v *)&h, *(h2v *)&w, acc, false);
#else
  float2 hf = __half22float2(*(const __half2 *)&h);
  float2 wf = __half22float2(*(const __half2 *)&w);
  return fmaf(hf.x, wf.x, fmaf(hf.y, wf.y, acc));
#endif
}

// ---- split-phase distributed-flag grid barrier, FENCELESS ----------------
__device__ __forceinline__ void arrive(unsigned *flags, unsigned gen, int tid, int blk) {
  __syncthreads();  // drains vmcnt(0) per wave: all agent-stores are in L3
  if (tid == 0) sth(flags + blk * 32, gen);
}
__device__ __forceinline__ void waitbar(unsigned *flags, unsigned gen, int tid) {
  {
    unsigned *f = flags + tid * 32;
    int g = 0;
    while (ldh(f) < gen) {
      __builtin_amdgcn_s_sleep(8);
      if (++g > (1 << 16)) break;  // safety: never deadlock the bench
    }
  }
  __syncthreads();  // all threads saw their flag; h reads below are uncached
}

// ---- half-dots: thread covers BOTH units (8 gate-rows) over 128 k2 -------
// Double-buffered 32-dword chunks; 256-thr blocks -> full VGPR budget
// (r7/r8 lesson: 512-thr blocks cap at 128 VGPR -> scratch spills).
__device__ __forceinline__ void dotq1(float *A, const uint4 *__restrict__ wq,
                                      const unsigned *__restrict__ hq) {
  unsigned ca[32], cb[32];
#pragma unroll
  for (int c = 0; c < 32; ++c) ca[c] = ldh(hq + c * 128);
  for (int j = 0; j < 4; j += 2) {
#pragma unroll
    for (int c = 0; c < 32; ++c) cb[c] = ldh(hq + ((j + 1) * 32 + c) * 128);
#pragma unroll
    for (int c = 0; c < 32; ++c) {
      int k2 = j * 32 + c;
      uint4 w0 = wq[k2 * 2], w1 = wq[k2 * 2 + 1];
      unsigned h = ca[c];
      A[0] = dot2(h, w0.x, A[0]); A[1] = dot2(h, w0.y, A[1]);
      A[2] = dot2(h, w0.z, A[2]); A[3] = dot2(h, w0.w, A[3]);
      A[4] = dot2(h, w1.x, A[4]); A[5] = dot2(h, w1.y, A[5]);
      A[6] = dot2(h, w1.z, A[6]); A[7] = dot2(h, w1.w, A[7]);
    }
#pragma unroll
    for (int c = 0; c < 32; ++c) ca[c] = ldh(hq + ((((j + 2) & 3)) * 32 + c) * 128);
#pragma unroll
    for (int c = 0; c < 32; ++c) {
      int k2 = (j + 1) * 32 + c;
      uint4 w0 = wq[k2 * 2], w1 = wq[k2 * 2 + 1];
      unsigned h = cb[c];
      A[0] = dot2(h, w0.x, A[0]); A[1] = dot2(h, w0.y, A[1]);
      A[2] = dot2(h, w0.z, A[2]); A[3] = dot2(h, w0.w, A[3]);
      A[4] = dot2(h, w1.x, A[4]); A[5] = dot2(h, w1.y, A[5]);
      A[6] = dot2(h, w1.z, A[6]); A[7] = dot2(h, w1.w, A[7]);
    }
  }
}
__device__ __forceinline__ void dotq2(float *A, const uint4 *__restrict__ w0q,
                                      const uint4 *__restrict__ w1q,
                                      const unsigned *__restrict__ hq) {
  unsigned ca[32], cb[32];
#pragma unroll
  for (int c = 0; c < 32; ++c) ca[c] = ldh(hq + c * 128);
  for (int j = 0; j < 4; j += 2) {
#pragma unroll
    for (int c = 0; c < 32; ++c) cb[c] = ldh(hq + ((j + 1) * 32 + c) * 128);
#pragma unroll
    for (int c = 0; c < 32; ++c) {
      int k2 = j * 32 + c;
      uint4 a0 = w0q[k2 * 2], a1 = w0q[k2 * 2 + 1];
      uint4 b0 = w1q[k2 * 2], b1 = w1q[k2 * 2 + 1];
      unsigned h = ca[c];
      A[0] = dot2(h, a0.x, A[0]);   A[1] = dot2(h, a0.y, A[1]);
      A[2] = dot2(h, a0.z, A[2]);   A[3] = dot2(h, a0.w, A[3]);
      A[4] = dot2(h, a1.x, A[4]);   A[5] = dot2(h, a1.y, A[5]);
      A[6] = dot2(h, a1.z, A[6]);   A[7] = dot2(h, a1.w, A[7]);
      A[8] = dot2(h, b0.x, A[8]);   A[9] = dot2(h, b0.y, A[9]);
      A[10] = dot2(h, b0.z, A[10]); A[11] = dot2(h, b0.w, A[11]);
      A[12] = dot2(h, b1.x, A[12]); A[13] = dot2(h, b1.y, A[13]);
      A[14] = dot2(h, b1.z, A[14]); A[15] = dot2(h, b1.w, A[15]);
    }
#pragma unroll
    for (int c = 0; c < 32; ++c) ca[c] = ldh(hq + ((((j + 2) & 3)) * 32 + c) * 128);
#pragma unroll
    for (int c = 0; c < 32; ++c) {
      int k2 = (j + 1) * 32 + c;
      uint4 a0 = w0q[k2 * 2], a1 = w0q[k2 * 2 + 1];
      uint4 b0 = w1q[k2 * 2], b1 = w1q[k2 * 2 + 1];
      unsigned h = cb[c];
      A[0] = dot2(h, a0.x, A[0]);   A[1] = dot2(h, a0.y, A[1]);
      A[2] = dot2(h, a0.z, A[2]);   A[3] = dot2(h, a0.w, A[3]);
      A[4] = dot2(h, a1.x, A[4]);   A[5] = dot2(h, a1.y, A[5]);
      A[6] = dot2(h, a1.z, A[6]);   A[7] = dot2(h, a1.w, A[7]);
      A[8] = dot2(h, b0.x, A[8]);   A[9] = dot2(h, b0.y, A[9]);
      A[10] = dot2(h, b0.z, A[10]); A[11] = dot2(h, b0.w, A[11]);
      A[12] = dot2(h, b1.x, A[12]); A[13] = dot2(h, b1.y, A[13]);
      A[14] = dot2(h, b1.z, A[14]); A[15] = dot2(h, b1.w, A[15]);
    }
  }
}

__device__ __forceinline__ void fc_emit(const unsigned *__restrict__ h1buf,
                                        const float *__restrict__ fcW,
                                        const float *__restrict__ fcb,
                                        float *__restrict__ out, int sIdx,
                                        int tid, int blk) {
  int q = tid >> 6, l = tid & 63;
  if (q < 3) {
    int o = blk * 3 + q, j = o >> 7, bb = o & 127;
    const unsigned *hc = h1buf + bb;
    const float2 *fw = (const float2 *)(fcW + j * 512);
    float acc = 0.f;
#pragma unroll
    for (int r = 0; r < 4; ++r) {
      int k2 = l + r * 64;
      unsigned d = ldh(hc + k2 * 128);
      float2 hf = __half22float2(*(const __half2 *)&d);
      float2 wv = fw[k2];
      acc = fmaf(wv.x, hf.x, acc);
      acc = fmaf(wv.y, hf.y, acc);
    }
#pragma unroll
    for (int off = 32; off; off >>= 1) acc += __shfl_down(acc, off, 64);
    if (l == 0) out[((size_t)bb * 256 + sIdx) * 6 + j] = acc + fcb[j];
  }
}

__global__ __launch_bounds__(256, 1) void seq2seq_kernel(P19 p) {
  const int tid = threadIdx.x;
  const int blk = blockIdx.x;
  const int b = tid & 127;   // batch lane
  const int kh = tid >> 7;   // k-half 0..1

  float *ws = p.ws;
  unsigned *flags = (unsigned *)ws;  // 256 flags, 128B-spaced
  unsigned *hpB = (unsigned *)(ws + 8256);
  unsigned *hp0r[2] = {hpB, hpB + 32768};           // h0 parity, [k2][b]
  unsigned *hp1r[2] = {hpB + 65536, hpB + 98304};   // h1 parity
  float *outp = ws + 8256 + 131072;                 // dec seed [j][b] 6*128
  float *srcT = outp + 768;                         // [t][i][b] 256*6*128

  // LDS: 7 matrices x 256 k2 x 2 units x (4 gates half2) = 56 KiB
  __shared__ __align__(16) uint4 wl4[3584];
  __shared__ float4 redux[6][128];  // 12 KiB: kh=1 partial-dot exchange
  __shared__ float wxe[48], wxd[48], bbuf[40];
  unsigned *wl1 = (unsigned *)wl4;

  {  // ---- stage weights (fp16 pairs) into LDS, once ----
    const float *mats[6] = {p.eWhh0, p.eWih1, p.eWhh1, p.dWhh0, p.dWih1, p.dWhh1};
    for (int e = tid; e < 12288; e += 256) {
      int k2 = e & 255, r = e >> 8;       // r 0..47
      int g = r & 3, uu = (r >> 2) & 1, m = r >> 3;
      const float *row = mats[m] + (size_t)(g * 512 + blk * 2 + uu) * 512;
      wl1[(m * 512 + k2 * 2 + uu) * 4 + g] = packh(row[2 * k2], row[2 * k2 + 1]);
    }
    for (int e = tid; e < 2048; e += 256) {  // W' = dec_Wih0 @ fcW -> slot 6
      int uu = e >> 10, rem = e & 1023, g = rem & 3, k2 = rem >> 2;
      const float *wr = p.dWih0 + (size_t)(g * 512 + blk * 2 + uu) * 6;
      float v0 = 0.f, v1 = 0.f;
#pragma unroll
      for (int i = 0; i < 6; ++i) {
        v0 = fmaf(wr[i], p.fcW[i * 512 + 2 * k2], v0);
        v1 = fmaf(wr[i], p.fcW[i * 512 + 2 * k2 + 1], v1);
      }
      wl1[(6 * 512 + k2 * 2 + uu) * 4 + g] = packh(v0, v1);
    }
    if (tid < 40) {  // fused biases: be0|be1|bd1|b''|bd0
      int f = tid >> 3, k = tid & 7, uu = k >> 2, g = k & 3;
      int r2 = g * 512 + blk * 2 + uu;
      float v;
      if (f == 0) v = p.ebih0[r2] + p.ebhh0[r2];
      else if (f == 1) v = p.ebih1[r2] + p.ebhh1[r2];
      else if (f == 2) v = p.dbih1[r2] + p.dbhh1[r2];
      else {
        v = p.dbih0[r2] + p.dbhh0[r2];
        if (f == 3)
#pragma unroll
          for (int i = 0; i < 6; ++i) v = fmaf(p.dWih0[(size_t)r2 * 6 + i], p.fcb[i], v);
      }
      bbuf[tid] = v;
    } else if (tid >= 64 && tid < 112) {
      int idx = tid - 64, uu = idx / 24, rem = idx % 24, g = rem / 6, i = rem % 6;
      wxe[idx] = p.eWih0[(size_t)(g * 512 + blk * 2 + uu) * 6 + i];
    } else if (tid >= 128 && tid < 176) {
      int idx = tid - 128, uu = idx / 24, rem = idx % 24, g = rem / 6, i = rem % 6;
      wxd[idx] = p.dWih0[(size_t)(g * 512 + blk * 2 + uu) * 6 + i];
    }
  }
  // ---- init: transpose src -> srcT; seed decoder input (agent stores: ----
  // ---- cross-block reads later must see them at the coherence point)  ----
  for (int e = blk * 256 + tid; e < 196608; e += 65536) {
    int bb = e & 127, rest = e >> 7, i = rest % 6, t = rest / 6;
    sthf(&srcT[t * 768 + i * 128 + bb], p.src[((size_t)bb * 256 + t) * 6 + i]);
  }
  {
    int g0 = blk * 256 + tid;
    if (g0 < 768) {
      int bb = g0 & 127, i = g0 >> 7;
      sthf(&outp[i * 128 + bb], p.src[((size_t)bb * 256 + 255) * 6 + i]);
    }
  }
  float c0[2] = {0.f, 0.f}, c1[2] = {0.f, 0.f};
  unsigned gen = 1;
  arrive(flags, gen, tid, blk);
  waitbar(flags, gen, tid);

#define WQ(m) (wl4 + (m) * 512 + kh * 256)
#define HST(buf) ((const unsigned *)(buf) + kh * 16384 + b)
#define RADD(gb, slot) { float4 v = redux[slot][b]; \
    G[(gb)] += v.x; G[(gb) + 1] += v.y; G[(gb) + 2] += v.z; G[(gb) + 3] += v.w; }

  // ================= encoder: layer0 & layer1 pipelined (lag 1) ============
  for (int t = 0; t <= 256; ++t) {
    float A16[16], A8[8];
#pragma unroll
    for (int i = 0; i < 16; ++i) A16[i] = 0.f;
#pragma unroll
    for (int i = 0; i < 8; ++i) A8[i] = 0.f;
    dotq2(A16, WQ(0), WQ(1), HST(hp0r[t & 1]));   // eWhh0 + eWih1 share h0
    dotq1(A8, WQ(2), HST(hp1r[(t + 1) & 1]));     // eWhh1 @ h1[t-2]
    if (kh) {
      redux[0][b] = make_float4(A16[0], A16[1], A16[2], A16[3]);
      redux[1][b] = make_float4(A16[4], A16[5], A16[6], A16[7]);
      redux[2][b] = make_float4(A16[8], A16[9], A16[10], A16[11]);
      redux[3][b] = make_float4(A16[12], A16[13], A16[14], A16[15]);
      redux[4][b] = make_float4(A8[0], A8[1], A8[2], A8[3]);
      redux[5][b] = make_float4(A8[4], A8[5], A8[6], A8[7]);
    }
    __syncthreads();
    if (kh == 0) {
      float G[24];
#pragma unroll
      for (int i = 0; i < 16; ++i) G[i] = A16[i];
#pragma unroll
      for (int i = 0; i < 8; ++i) G[16 + i] = A8[i];
      { RADD(0, 0) RADD(4, 1) RADD(8, 2) RADD(12, 3) RADD(16, 4) RADD(20, 5) }
      if (t < 256) {  // layer0
        float xv[6], h0v[2];
#pragma unroll
        for (int i = 0; i < 6; ++i) xv[i] = srcT[t * 768 + i * 128 + b];
#pragma unroll
        for (int uu = 0; uu < 2; ++uu) {
          float g4[4];
#pragma unroll
          for (int g = 0; g < 4; ++g) {
            float v = G[uu * 4 + g] + bbuf[uu * 4 + g];
#pragma unroll
            for (int i = 0; i < 6; ++i) v = fmaf(wxe[uu * 24 + g * 6 + i], xv[i], v);
            g4[g] = v;
          }
          float ig = sigf(g4[0]), fg = sigf(g4[1]), gg = tanhf(g4[2]), og = sigf(g4[3]);
          c0[uu] = fg * c0[uu] + ig * gg;
          h0v[uu] = og * tanhf(c0[uu]);
        }
        sth(&hp0r[(t + 1) & 1][blk * 128 + b], packh(h0v[0], h0v[1]));
      }
      if (t >= 1) {  // layer1
        float h1v[2];
#pragma unroll
        for (int uu = 0; uu < 2; ++uu) {
          float g4[4];
#pragma unroll
          for (int g = 0; g < 4; ++g)
            g4[g] = G[8 + uu * 4 + g] + G[16 + uu * 4 + g] + bbuf[8 + uu * 4 + g];
          float ig = sigf(g4[0]), fg = sigf(g4[1]), gg = tanhf(g4[2]), og = sigf(g4[3]);
          c1[uu] = fg * c1[uu] + ig * gg;
          h1v[uu] = og * tanhf(c1[uu]);
        }
        sth(&hp1r[t & 1][blk * 128 + b], packh(h1v[0], h1v[1]));
      }
    }
    arrive(flags, ++gen, tid, blk);
    waitbar(flags, gen, tid);
  }
  // enc final: h0 in hp0r[0], h1 in hp1r[0]; c0,c1 in registers.

  // ========== decoder: 2 rounds/step, pre-dots hide barrier waits ==========
  for (int s = 0; s < 256; ++s) {
    // ---- R_A: dec layer0 (+ W'@h1 fused fc; saves Whh1d partial for R_B) --
    float A3[8];
#pragma unroll
    for (int i = 0; i < 8; ++i) A3[i] = 0.f;
    dotq1(A3, WQ(3), HST(hp0r[s & 1]));  // pre-wait: stream synced last gen
    if (s) waitbar(flags, gen, tid);
    float AA[16];
#pragma unroll
    for (int i = 0; i < 16; ++i) AA[i] = 0.f;
    if (s == 0) {
      dotq1(AA + 8, WQ(5), HST(hp1r[0]));  // Whh1d partial only
    } else {
      dotq2(AA, WQ(6), WQ(5), HST(hp1r[s & 1]));  // W' + Whh1d share h1
      fc_emit(hp1r[s & 1], p.fcW, p.fcb, p.out, s - 1, tid, blk);
    }
    if (kh) {
      redux[0][b] = make_float4(A3[0], A3[1], A3[2], A3[3]);
      redux[1][b] = make_float4(A3[4], A3[5], A3[6], A3[7]);
      redux[2][b] = make_float4(AA[0], AA[1], AA[2], AA[3]);
      redux[3][b] = make_float4(AA[4], AA[5], AA[6], AA[7]);
    }
    __syncthreads();
    if (kh == 0) {
      float G[8];
#pragma unroll
      for (int i = 0; i < 8; ++i) G[i] = A3[i] + AA[i];
      { RADD(0, 0) RADD(4, 1) RADD(0, 2) RADD(4, 3) }
      float bq[8];
      if (s == 0) {
        float xv[6];
#pragma unroll
        for (int i = 0; i < 6; ++i) xv[i] = ldhf(&outp[i * 128 + b]);
#pragma unroll
        for (int k = 0; k < 8; ++k) {
          int uu = k >> 2, g = k & 3;
          float v = bbuf[32 + k];
#pragma unroll
          for (int i = 0; i < 6; ++i) v = fmaf(wxd[uu * 24 + g * 6 + i], xv[i], v);
          bq[k] = v;
        }
      } else {
#pragma unroll
        for (int k = 0; k < 8; ++k) bq[k] = bbuf[24 + k];
      }
      float h0v[2];
#pragma unroll
      for (int uu = 0; uu < 2; ++uu) {
        float ig = sigf(G[uu * 4 + 0] + bq[uu * 4 + 0]);
        float fg = sigf(G[uu * 4 + 1] + bq[uu * 4 + 1]);
        float gg = tanhf(G[uu * 4 + 2] + bq[uu * 4 + 2]);
        float og = sigf(G[uu * 4 + 3] + bq[uu * 4 + 3]);
        c0[uu] = fg * c0[uu] + ig * gg;
        h0v[uu] = og * tanhf(c0[uu]);
      }
      sth(&hp0r[(s + 1) & 1][blk * 128 + b], packh(h0v[0], h0v[1]));
    }
    arrive(flags, ++gen, tid, blk);
    // ---- R_B: dec layer1 = Whh1d-partial (saved) + Wih1d @ h0[s] (new) ----
    waitbar(flags, gen, tid);
    float A4[8];
#pragma unroll
    for (int i = 0; i < 8; ++i) A4[i] = AA[8 + i];  // saved partial
    dotq1(A4, WQ(4), HST(hp0r[(s + 1) & 1]));
    if (kh) {
      redux[0][b] = make_float4(A4[0], A4[1], A4[2], A4[3]);
      redux[1][b] = make_float4(A4[4], A4[5], A4[6], A4[7]);
    }
    __syncthreads();
    if (kh == 0) {
      float G[8];
#pragma unroll
      for (int i = 0; i < 8; ++i) G[i] = A4[i];
      { RADD(0, 0) RADD(4, 1) }
      float h1v[2];
#pragma unroll
      for (int uu = 0; uu < 2; ++uu) {
        float ig = sigf(G[uu * 4 + 0] + bbuf[16 + uu * 4 + 0]);
        float fg = sigf(G[uu * 4 + 1] + bbuf[16 + uu * 4 + 1]);
        float gg = tanhf(G[uu * 4 + 2] + bbuf[16 + uu * 4 + 2]);
        float og = sigf(G[uu * 4 + 3] + bbuf[16 + uu * 4 + 3]);
        c1[uu] = fg * c1[uu] + ig * gg;
        h1v[uu] = og * tanhf(c1[uu]);
      }
      sth(&hp1r[(s + 1) & 1][blk * 128 + b], packh(h1v[0], h1v[1]));
    }
    arrive(flags, ++gen, tid, blk);
  }
  waitbar(flags, gen, tid);
  fc_emit(hp1r[0], p.fcW, p.fcb, p.out, 255, tid, blk);  // tail out[255]
}

extern "C" void kernel_launch(void *const *d_in, const int *in_sizes, int n_in,
                              void *d_out, int out_size, void *d_ws, size_t ws_size,
                              hipStream_t stream) {
  (void)in_sizes; (void)n_in; (void)out_size; (void)ws_size;
  P19 p;
  p.src = (const float *)d_in[0];
  p.eWih0 = (const float *)d_in[1];  p.eWhh0 = (const float *)d_in[2];
  p.ebih0 = (const float *)d_in[3];  p.ebhh0 = (const float *)d_in[4];
  p.eWih1 = (const float *)d_in[5];  p.eWhh1 = (const float *)d_in[6];
  p.ebih1 = (const float *)d_in[7];  p.ebhh1 = (const float *)d_in[8];
  p.dWih0 = (const float *)d_in[9];  p.dWhh0 = (const float *)d_in[10];
  p.dbih0 = (const float *)d_in[11]; p.dbhh0 = (const float *)d_in[12];
  p.dWih1 = (const float *)d_in[13]; p.dWhh1 = (const float *)d_in[14];
  p.dbih1 = (const float *)d_in[15]; p.dbhh1 = (const float *)d_in[16];
  p.fcW = (const float *)d_in[17];   p.fcb = (const float *)d_in[18];
  p.out = (float *)d_out;
  p.ws = (float *)d_ws;

  // zero flags + 4 packed-h parity buffers (outp/srcT written by kernel init)
  hipMemsetAsync(d_ws, 0, (size_t)(8256 + 4 * 32768) * sizeof(float), stream);
  seq2seq_kernel<<<dim3(256), dim3(256), 0, stream>>>(p);
}